// Round 1
// baseline (453.708 us; speedup 1.0000x reference)
//
#include <hip/hip_runtime.h>
#include <math.h>

// Cumulative max along axis 0 of a [64, 64, 128, 128] fp32 tensor.
// N = 64 scan steps, inner = 64*128*128 = 1,048,576 elements.
// Memory-bound streaming op, traffic already minimal (256 MiB in + 256 MiB out).
// This version attacks memory-level parallelism and cache thrash:
//  - rolling register prefetch (depth 8): 8 independent global loads always in
//    flight per wave (vs ~1-2 when load/fmax/store are interleaved), fully
//    unrolled so pre[n % 8] is a compile-time register index (no scratch).
//  - nontemporal load/store: streams are touched exactly once; 512 MiB working
//    set is 2x the 256 MiB LLC, so bypassing allocation avoids eviction churn.

#define SCAN_N   64
#define INNER4   (64 * 128 * 128 / 4)   // 262,144 float4 per slice
#define PF       8                       // prefetch depth (loads in flight)

typedef float f32x4 __attribute__((ext_vector_type(4)));

__global__ __launch_bounds__(256) void cummax_axis0_kernel(
        const f32x4* __restrict__ x, f32x4* __restrict__ out) {
    const int i = blockIdx.x * blockDim.x + threadIdx.x;  // inner float4 idx
    if (i >= INNER4) return;

    const f32x4* px = x + i;
    f32x4*       po = out + i;

    // Prologue: fill the prefetch ring with slices 0..PF-1.
    f32x4 pre[PF];
    #pragma unroll
    for (int k = 0; k < PF; ++k)
        pre[k] = __builtin_nontemporal_load(px + (size_t)k * INNER4);

    f32x4 m;
    m[0] = -INFINITY; m[1] = -INFINITY; m[2] = -INFINITY; m[3] = -INFINITY;

    // Fully unrolled scan: consume pre[n%PF], immediately refill it with
    // slice n+PF. Keeps PF loads outstanding at all times; stores ride along.
    #pragma unroll
    for (int n = 0; n < SCAN_N; ++n) {
        const f32x4 v = pre[n % PF];            // compile-time index
        if (n + PF < SCAN_N)
            pre[n % PF] = __builtin_nontemporal_load(px + (size_t)(n + PF) * INNER4);
        #pragma unroll
        for (int c = 0; c < 4; ++c)
            m[c] = fmaxf(m[c], v[c]);
        __builtin_nontemporal_store(m, po + (size_t)n * INNER4);
    }
}

extern "C" void kernel_launch(void* const* d_in, const int* in_sizes, int n_in,
                              void* d_out, int out_size, void* d_ws, size_t ws_size,
                              hipStream_t stream) {
    const f32x4* x = (const f32x4*)d_in[0];
    f32x4* out = (f32x4*)d_out;

    const int threads = 256;
    const int blocks = INNER4 / threads;  // 1024 blocks = 4 per CU, 16 waves/CU
    cummax_axis0_kernel<<<blocks, threads, 0, stream>>>(x, out);
}

// Round 2
// 436.295 us; speedup vs baseline: 1.0399x; 1.0399x over previous
//
#include <hip/hip_runtime.h>

// Cumulative max along axis 0 of a [64, 64, 128, 128] fp32 tensor.
// N = 64 scan steps, inner = 64*128*128 = 1,048,576 elements.
// Memory-bound streaming op: thread t owns inner float4 index t, walks the
// scan axis with a running max in registers. Fully coalesced loads/stores.
//
// R1 post-mortem: nontemporal LOADS regressed 24% — input (256 MiB) is
// LLC-resident (LLC = 256 MiB) across iterations and nt loads bypassed it.
// R2: plain loads (keep LLC input hits) + nontemporal STORES only (output is
// never re-read; keep the 256 MiB write stream from evicting the input).

#define SCAN_N   64
#define INNER4   (64 * 128 * 128 / 4)   // 262,144 float4 per slice

typedef float f32x4 __attribute__((ext_vector_type(4)));

__global__ __launch_bounds__(256) void cummax_axis0_kernel(
        const f32x4* __restrict__ x, f32x4* __restrict__ out) {
    const int i = blockIdx.x * blockDim.x + threadIdx.x;  // inner float4 idx
    if (i >= INNER4) return;

    // n = 0: initialize running max
    f32x4 m = x[i];
    __builtin_nontemporal_store(m, out + i);

    int off = INNER4 + i;   // max index 64*262144 = 16.7M < 2^31, int is fine
    #pragma unroll 4
    for (int n = 1; n < SCAN_N; ++n, off += INNER4) {
        const f32x4 v = x[off];
        m[0] = fmaxf(m[0], v[0]);
        m[1] = fmaxf(m[1], v[1]);
        m[2] = fmaxf(m[2], v[2]);
        m[3] = fmaxf(m[3], v[3]);
        __builtin_nontemporal_store(m, out + off);
    }
}

extern "C" void kernel_launch(void* const* d_in, const int* in_sizes, int n_in,
                              void* d_out, int out_size, void* d_ws, size_t ws_size,
                              hipStream_t stream) {
    const f32x4* x = (const f32x4*)d_in[0];
    f32x4* out = (f32x4*)d_out;

    const int threads = 256;
    const int blocks = INNER4 / threads;  // 1024 blocks = 4/CU, 16 waves/CU
    cummax_axis0_kernel<<<blocks, threads, 0, stream>>>(x, out);
}

// Round 3
// 432.867 us; speedup vs baseline: 1.0481x; 1.0079x over previous
//
#include <hip/hip_runtime.h>

// Cumulative max along axis 0 of a [64, 64, 128, 128] fp32 tensor.
// N = 64 scan steps, inner = 64*128*128 = 1,048,576 elements.
// Memory-bound streaming op, traffic minimal (256 MiB read + 256 MiB write).
//
// R1: nt loads + depth-8 ring: +24 us  (nt loads kill L2/LLC write/read path)
// R2: nt stores only:          +7 us   (stores want to retire at L2)
// -> both nontemporal paths closed; plain loads/stores.
//
// R3: occupancy. float4 granularity fixed the grid at 262,144 threads =
// 16 waves/CU (half of the 32-wave capacity). Mixed read+write streams need
// dense request interleaving across waves to hide DRAM turnaround; switch to
// float2/thread -> 524,288 threads = 2048 blocks = 32 waves/CU (max occ).
// 8 B/lane x 64 lanes = 512 B per load instr, still fully coalesced.

#define SCAN_N   64
#define INNER2   (64 * 128 * 128 / 2)   // 524,288 float2 per slice

typedef float f32x2 __attribute__((ext_vector_type(2)));

__global__ __launch_bounds__(256) void cummax_axis0_kernel(
        const f32x2* __restrict__ x, f32x2* __restrict__ out) {
    const int i = blockIdx.x * blockDim.x + threadIdx.x;  // inner float2 idx
    if (i >= INNER2) return;

    // n = 0: initialize running max
    f32x2 m = x[i];
    out[i] = m;

    int off = INNER2 + i;   // max elem index 64*524288 = 33.5M < 2^31, int ok
    #pragma unroll 4
    for (int n = 1; n < SCAN_N; ++n, off += INNER2) {
        const f32x2 v = x[off];
        m[0] = fmaxf(m[0], v[0]);
        m[1] = fmaxf(m[1], v[1]);
        out[off] = m;
    }
}

extern "C" void kernel_launch(void* const* d_in, const int* in_sizes, int n_in,
                              void* d_out, int out_size, void* d_ws, size_t ws_size,
                              hipStream_t stream) {
    const f32x2* x = (const f32x2*)d_in[0];
    f32x2* out = (f32x2*)d_out;

    const int threads = 256;
    const int blocks = INNER2 / threads;  // 2048 blocks = 8/CU, 32 waves/CU
    cummax_axis0_kernel<<<blocks, threads, 0, stream>>>(x, out);
}